// Round 11
// baseline (42540.930 us; speedup 1.0000x reference)
//
#include <hip/hip_runtime.h>
#include <hip/hip_bf16.h>

// Problem constants
#define BATCH 1024
#define SEQ   350
#define LAT   512
#define VOC   41
#define H0D   512
#define H1D   256
#define H2D   128
#define H3D   32
#define G1    768   // 3*H1D
#define G2    384   // 3*H2D
#define G3    96    // 3*H3D
#define SOS   1

// ws layout (floats) — PLANAR k-major, identical to rounds 2/7/9 (proven layout;
// R3/R10 proved any interleaved deviation doubles FETCH and regresses).
#define O_HH0   0         // wt_hh0 [256k][768]
#define O_IH1   196608    // wt_ih1 [256k][384]
#define O_HH1   294912    // wt_hh1 [128k][384]
#define O_IH2   344064    // wt_ih2 [128k][96]
#define O_HH2   356352    // wt_hh2 [32k][96]
#define O_PROJ  359424    // wt_proj [32][41]
#define O_TAB   360736    // gi0 table [41][768]
#define WS_FLOATS 392224

#define RT 4     // batch rows per block
#define NT 1024  // threads per block (16 waves) — gate-de-fused decomposition

__global__ void setup_kernel(const float* __restrict__ Whh0, const float* __restrict__ Wih1,
                             const float* __restrict__ Whh1, const float* __restrict__ Wih2,
                             const float* __restrict__ Whh2, const float* __restrict__ Wproj,
                             const float* __restrict__ Wemb, const float* __restrict__ bemb,
                             const float* __restrict__ Wih0, const float* __restrict__ bih0,
                             float* __restrict__ ws) {
  int idx = blockIdx.x * blockDim.x + threadIdx.x;
  if (idx < 196608) { int o = idx % G1, k = idx / G1; ws[O_HH0 + k*G1 + o] = Whh0[o*H1D + k]; return; }
  idx -= 196608;
  if (idx < 98304)  { int o = idx % G2, k = idx / G2; ws[O_IH1 + k*G2 + o] = Wih1[o*H1D + k]; return; }
  idx -= 98304;
  if (idx < 49152)  { int o = idx % G2, k = idx / G2; ws[O_HH1 + k*G2 + o] = Whh1[o*H2D + k]; return; }
  idx -= 49152;
  if (idx < 12288)  { int o = idx % G3, k = idx / G3; ws[O_IH2 + k*G3 + o] = Wih2[o*H2D + k]; return; }
  idx -= 12288;
  if (idx < 3072)   { int o = idx % G3, k = idx / G3; ws[O_HH2 + k*G3 + o] = Whh2[o*H3D + k]; return; }
  idx -= 3072;
  if (idx < 1312)   { int o = idx % VOC, k = idx / VOC; ws[O_PROJ + k*VOC + o] = Wproj[o*H3D + k]; return; }
  idx -= 1312;
  if (idx < 31488) {
    // gi0 table: exact (f64-accumulated) x@Wih0.T + bih0 per token value.
    int o = idx % G1, v = idx / G1;
    double acc = (double)bih0[o];
    const float* wrow = Wih0 + (size_t)o * H0D;
    for (int k = 0; k < H0D; ++k)
      acc += ((double)Wemb[k*VOC + v] + (double)bemb[k]) * (double)wrow[k];
    ws[O_TAB + v*G1 + o] = (float)acc;
  }
}

__device__ __forceinline__ float sigf(float x) { return 1.0f / (1.0f + expf(-x)); }

__global__ __launch_bounds__(NT, 4) void gru_persist(
    const float* __restrict__ latent, const int* __restrict__ tgt,
    const float* __restrict__ Winit, const float* __restrict__ binit,
    const float* __restrict__ bhh0,
    const float* __restrict__ bih1, const float* __restrict__ bhh1,
    const float* __restrict__ bih2, const float* __restrict__ bhh2,
    const float* __restrict__ bproj,
    const float* __restrict__ ws, float* __restrict__ out)
{
  const int tid = threadIdx.x;
  const int r0 = blockIdx.x * RT;
  const int lane = tid & 63;
  const int wv = tid >> 6;   // wave id 0..15

  float* __restrict__ out_logits = out;
  float* __restrict__ out_pred = out + (size_t)BATCH * SEQ * VOC;

  __shared__ __align__(16) float h0s[2][RT][H1D];  // 8 KB (double-buffered)
  __shared__ __align__(16) float h1s[RT][H2D];     // 2 KB (in-place, as R9)
  __shared__ __align__(16) float h2s[RT][H3D];     // 0.5 KB (in-place, as R9)
  __shared__ float scA[2][RT][G1];     // 24 KB  [kh][r][o] stage-A gate partials
  __shared__ float scBi[2][RT][G2];    // 12 KB  [kh][r][o] gi1 partials
  __shared__ float scBh[2][RT][G2];    // 12 KB  [kh][r][o] gh1 partials
  __shared__ float scC[10][RT][G3];    // 15 KB  [slice][r][o] stage-C partials
  __shared__ float projS[H3D * VOC];   // 5.1 KB
  __shared__ int   toksAll[RT][SEQ];   // 5.5 KB
  // total ~85 KB -> 1 block/CU, 16 waves (4/SIMD)

  // ---- de-fused unit mappings (all wave-aligned where it matters) ----
  // A-dot pass1 (all 1024 threads): tid<768 -> (kh=0, o=tid); else (kh=1, o=tid-768)
  const int oA1  = (tid < 768) ? tid : tid - 768;
  const int khA1 = (tid < 768) ? 0 : 1;
  // A-dot pass2 (tid<512): (kh=1, o=256+tid)
  // A-epi (all threads): unit (rA, jAe)
  const int rA = tid >> 8, jAe = tid & 255;
  // B-dot gi1 (tid<768): kh = tid/384, o = tid%384
  const int khBi = (tid < 768) ? (tid / 384) : 0;
  const int oBi  = (tid < 768) ? (tid % 384) : 0;
  // B-dot gh1: tid>=768 -> id=tid-768 (0..255); tid<512 -> id=256+tid (256..767)
  const int idBh = (tid >= 768) ? (tid - 768) : (256 + tid);
  const int khBh = idBh / 384, oBh = idBh % 384;
  const bool actBh = (tid >= 768) || (tid < 512);
  // B-epi (tid<512): unit (rBe, jbe)
  const int rBe = (tid >> 7) & 3, jbe = tid & 127;
  // C-dot gi2 (tid<768): sc = tid/96, o = tid%96 ; gh2 (768..959): sc2, o
  const int scC1 = tid / 96, oC1 = tid - scC1 * 96;          // valid for tid<768
  const int idC2 = tid - 768;
  const int scC2 = idC2 / 96, oC2 = idC2 - scC2 * 96;        // valid for 768<=tid<960

  // ---- t-invariant biases (per-role) ----
  const float bA_r = bhh0[jAe], bA_z = bhh0[256 + jAe], bA_n = bhh0[512 + jAe];
  const float bB_ir = bih1[jbe], bB_iz = bih1[128 + jbe], bB_in = bih1[256 + jbe];
  const float bB_hr = bhh1[jbe], bB_hz = bhh1[128 + jbe], bB_hn = bhh1[256 + jbe];
  const int jj2 = lane & 31;
  const float bC_ir = bih2[jj2], bC_iz = bih2[32 + jj2], bC_in = bih2[64 + jj2];
  const float bC_hr = bhh2[jj2], bC_hz = bhh2[32 + jj2], bC_hn = bhh2[64 + jj2];
  const int cpr = (lane < VOC) ? lane : 0;
  const float bP = bproj[cpr];

  // ---- one-time staging ----
  for (int i = tid; i < RT * SEQ; i += NT) {
    int r = i / SEQ, tt = i - r * SEQ;
    toksAll[r][tt] = (tt == 0) ? SOS : tgt[(size_t)(r0 + r) * SEQ + tt];
  }
  for (int i = tid; i < H3D * VOC; i += NT) projS[i] = ws[O_PROJ + i];

  // ---- init hidden states (f64, one-time; exact early-step logits) ----
  for (int idx = tid; idx < RT * 416; idx += NT) {
    int r = idx / 416, jj = idx - r * 416;
    const float* lrow = latent + (size_t)(r0 + r) * LAT;
    const float* wrow = Winit + (size_t)jj * LAT;
    double acc = (double)binit[jj];
    for (int k = 0; k < LAT; ++k) acc += (double)lrow[k] * (double)wrow[k];
    float a = (float)acc;
    if (jj < H1D) h0s[0][r][jj] = a;
    else if (jj < H1D + H2D) h1s[r][jj - H1D] = a;
    else h2s[r][jj - H1D - H2D] = a;
  }
  __syncthreads();

  int cur0 = 0;

  for (int t = 0; t < SEQ; ++t) {
    // ======== Stage A dot: units (kh, o) — per-accumulator k-order identical
    //          to R9's fused loop (kb ascending, u 0..3). ========
    {
      float a1[RT];
      #pragma unroll
      for (int r = 0; r < RT; ++r) a1[r] = 0.0f;
      const float* __restrict__ w1 = ws + O_HH0 + oA1;
      const int k0 = khA1 << 7;
      for (int kb = k0; kb < k0 + 128; kb += 4) {
        float4 hv[RT];
        #pragma unroll
        for (int r = 0; r < RT; ++r) hv[r] = *(const float4*)&h0s[cur0][r][kb];
        #pragma unroll
        for (int u = 0; u < 4; ++u) {
          const float w = w1[(size_t)(kb + u) * G1];
          #pragma unroll
          for (int r = 0; r < RT; ++r)
            a1[r] = fmaf(((const float*)&hv[r])[u], w, a1[r]);
        }
      }
      #pragma unroll
      for (int r = 0; r < RT; ++r) scA[khA1][r][oA1] = a1[r];

      if (tid < 512) {   // pass 2: (kh=1, o=256+tid)
        const int o2 = 256 + tid;
        float a2[RT];
        #pragma unroll
        for (int r = 0; r < RT; ++r) a2[r] = 0.0f;
        const float* __restrict__ w2 = ws + O_HH0 + o2;
        for (int kb = 128; kb < 256; kb += 4) {
          float4 hv[RT];
          #pragma unroll
          for (int r = 0; r < RT; ++r) hv[r] = *(const float4*)&h0s[cur0][r][kb];
          #pragma unroll
          for (int u = 0; u < 4; ++u) {
            const float w = w2[(size_t)(kb + u) * G1];
            #pragma unroll
            for (int r = 0; r < RT; ++r)
              a2[r] = fmaf(((const float*)&hv[r])[u], w, a2[r]);
          }
        }
        #pragma unroll
        for (int r = 0; r < RT; ++r) scA[1][r][o2] = a2[r];
      }
    }
    __syncthreads();  // Bar1: scA complete

    // ======== Stage A epilogue: unit (rA, jAe). Association replicates R9 EPIA:
    //          rows 0,1: ((tx + P_kh0) + P_kh1) + b ; rows 2,3: ((tx + P_kh1) + P_kh0) + b. ========
    {
      const float* trow = ws + O_TAB + (size_t)toksAll[rA][t] * G1;
      const float tx = trow[jAe], ty = trow[256 + jAe], tz = trow[512 + jAe];
      const float p0r = scA[0][rA][jAe],        p1r = scA[1][rA][jAe];
      const float p0z = scA[0][rA][256 + jAe],  p1z = scA[1][rA][256 + jAe];
      const float p0n = scA[0][rA][512 + jAe],  p1n = scA[1][rA][512 + jAe];
      float gR, gZ, ghN;
      if (rA < 2) {
        gR  = tx + p0r + p1r + bA_r;
        gZ  = ty + p0z + p1z + bA_z;
        ghN =      p0n + p1n + bA_n;
      } else {
        gR  = tx + p1r + p0r + bA_r;
        gZ  = ty + p1z + p0z + bA_z;
        ghN =      p1n + p0n + bA_n;
      }
      const float rg = sigf(gR);
      const float zg = sigf(gZ);
      const float ng = tanhf(fmaf(rg, ghN, tz));
      h0s[cur0 ^ 1][rA][jAe] = (1.0f - zg) * ng + zg * h0s[cur0][rA][jAe];
    }
    __syncthreads();  // Bar2: h0 new visible

    // ======== Stage B dot: gi1 units (khBi, oBi) on tid<768 over new h0;
    //          gh1 units (khBh, oBh) on actBh over old h1. ========
    {
      if (tid < 768) {
        float b1[RT];
        #pragma unroll
        for (int r = 0; r < RT; ++r) b1[r] = 0.0f;
        const float* __restrict__ w = ws + O_IH1 + oBi;
        const int k0 = khBi << 7;
        for (int kb = k0; kb < k0 + 128; kb += 4) {
          float4 hv[RT];
          #pragma unroll
          for (int r = 0; r < RT; ++r) hv[r] = *(const float4*)&h0s[cur0 ^ 1][r][kb];
          #pragma unroll
          for (int u = 0; u < 4; ++u) {
            const float wq = w[(size_t)(kb + u) * G2];
            #pragma unroll
            for (int r = 0; r < RT; ++r)
              b1[r] = fmaf(((const float*)&hv[r])[u], wq, b1[r]);
          }
        }
        #pragma unroll
        for (int r = 0; r < RT; ++r) scBi[khBi][r][oBi] = b1[r];
      }
      if (actBh) {
        float q1[RT];
        #pragma unroll
        for (int r = 0; r < RT; ++r) q1[r] = 0.0f;
        const float* __restrict__ w = ws + O_HH1 + oBh;
        const int k0 = khBh << 6;
        for (int kb = k0; kb < k0 + 64; kb += 4) {
          float4 hv[RT];
          #pragma unroll
          for (int r = 0; r < RT; ++r) hv[r] = *(const float4*)&h1s[r][kb];
          #pragma unroll
          for (int u = 0; u < 4; ++u) {
            const float wq = w[(size_t)(kb + u) * G2];
            #pragma unroll
            for (int r = 0; r < RT; ++r)
              q1[r] = fmaf(((const float*)&hv[r])[u], wq, q1[r]);
          }
        }
        #pragma unroll
        for (int r = 0; r < RT; ++r) scBh[khBh][r][oBh] = q1[r];
      }
    }
    __syncthreads();  // Bar3: scBi/scBh complete; all old-h1 reads done

    // ======== Stage B epilogue (tid<512): unit (rBe, jbe). Orders replicate R9:
    //          gi: (P0+P1)+b all rows; gh: rows 0,1 (Q0+Q1)+b, rows 2,3 (Q1+Q0)+b. ========
    if (tid < 512) {
      const float giR = scBi[0][rBe][jbe] + scBi[1][rBe][jbe] + bB_ir;
      const float giZ = scBi[0][rBe][128 + jbe] + scBi[1][rBe][128 + jbe] + bB_iz;
      const float giN = scBi[0][rBe][256 + jbe] + scBi[1][rBe][256 + jbe] + bB_in;
      float ghR, ghZ, ghN;
      if (rBe < 2) {
        ghR = scBh[0][rBe][jbe] + scBh[1][rBe][jbe] + bB_hr;
        ghZ = scBh[0][rBe][128 + jbe] + scBh[1][rBe][128 + jbe] + bB_hz;
        ghN = scBh[0][rBe][256 + jbe] + scBh[1][rBe][256 + jbe] + bB_hn;
      } else {
        ghR = scBh[1][rBe][jbe] + scBh[0][rBe][jbe] + bB_hr;
        ghZ = scBh[1][rBe][128 + jbe] + scBh[0][rBe][128 + jbe] + bB_hz;
        ghN = scBh[1][rBe][256 + jbe] + scBh[0][rBe][256 + jbe] + bB_hn;
      }
      const float rg = sigf(giR + ghR);
      const float zg = sigf(giZ + ghZ);
      const float ng = tanhf(fmaf(rg, ghN, giN));
      h1s[rBe][jbe] = (1.0f - zg) * ng + zg * h1s[rBe][jbe];
    }
    __syncthreads();  // Bar4: h1 new visible

    // ======== Stage C dot: gi2 units (scC1, oC1) tid<768 over new h1;
    //          gh2 units (scC2, oC2) tid 768..959 over old h2. ========
    {
      if (tid < 768) {
        float c1[RT];
        #pragma unroll
        for (int r = 0; r < RT; ++r) c1[r] = 0.0f;
        const int k0 = scC1 * 16;
        for (int kk = 0; kk < 16; ++kk) {
          const int k = k0 + kk;
          const float w = ws[O_IH2 + (size_t)k * G3 + oC1];
          #pragma unroll
          for (int r = 0; r < RT; ++r)
            c1[r] = fmaf(h1s[r][k], w, c1[r]);
        }
        #pragma unroll
        for (int r = 0; r < RT; ++r) scC[scC1][r][oC1] = c1[r];
      } else if (tid < 960) {
        float c2[RT];
        #pragma unroll
        for (int r = 0; r < RT; ++r) c2[r] = 0.0f;
        const int k0 = scC2 * 16;
        for (int kk = 0; kk < 16; ++kk) {
          const int k = k0 + kk;
          const float w = ws[O_HH2 + (size_t)k * G3 + oC2];
          #pragma unroll
          for (int r = 0; r < RT; ++r)
            c2[r] = fmaf(h2s[r][k], w, c2[r]);
        }
        #pragma unroll
        for (int r = 0; r < RT; ++r) scC[8 + scC2][r][oC2] = c2[r];
      }
    }
    __syncthreads();  // Bar5: scC complete; all old-h2 reads done

    // ======== Stage C combine + projection + argmax on waves 0-3 (one row each);
    //          waves 4-15 fall through into stage A of t+1 (sync via Bar1(t+1)). ========
    if (wv < 4) {
      const int r = wv;
      float h2f = 0.0f;
      if (lane < 32) {
        const int jj = lane;
        float giR = bC_ir, giZ = bC_iz, giN = bC_in;
        #pragma unroll
        for (int s = 0; s < 8; ++s) {
          giR += scC[s][r][jj];
          giZ += scC[s][r][32 + jj];
          giN += scC[s][r][64 + jj];
        }
        const float ghR = scC[8][r][jj] + scC[9][r][jj] + bC_hr;
        const float ghZ = scC[8][r][32 + jj] + scC[9][r][32 + jj] + bC_hz;
        const float ghN = scC[8][r][64 + jj] + scC[9][r][64 + jj] + bC_hn;
        const float rg = sigf(giR + ghR);
        const float zg = sigf(giZ + ghZ);
        const float ng = tanhf(fmaf(rg, ghN, giN));
        h2f = (1.0f - zg) * ng + zg * h2s[r][jj];
        h2s[r][jj] = h2f;   // next reader (gh2 at t+1) crosses Bar1..Bar4(t+1)
      }
      // projection: lane c computes logit c; h2 broadcast from lanes 0..31
      float acc = bP;
      #pragma unroll
      for (int k = 0; k < H3D; ++k) {
        const float hk = __shfl(h2f, k);
        acc = fmaf(hk, projS[k * VOC + cpr], acc);
      }
      if (lane < VOC)
        out_logits[((size_t)(r0 + r) * SEQ + t) * VOC + lane] = acc;
      // wave-wide argmax, first-max tie-break to match jnp.argmax
      float val = (lane < VOC) ? acc : -3.402823466e38f;
      int idx = lane;
      #pragma unroll
      for (int off = 32; off > 0; off >>= 1) {
        const float ov = __shfl_xor(val, off);
        const int   oi = __shfl_xor(idx, off);
        if (ov > val || (ov == val && oi < idx)) { val = ov; idx = oi; }
      }
      if (lane == 0)
        out_pred[(size_t)(r0 + r) * SEQ + t] = (float)idx;
    }
    cur0 ^= 1;
    // Hazard audit (5 uniform barriers/step):
    //  h0s[cur0]: A-dot(t) reads; next writer A-epi(t+1) after Bar1(t+1) — OK.
    //  h0s[cur0^1]: W by A-epi(t) pre-Bar2; R by gi1(t) post-Bar2 and A-dot(t+1)
    //    (early waves post-Bar5(t)) — OK.
    //  scA: W pre-Bar1 / R (A-epi) pre-Bar2; next W at A-dot(t+1) — early waves
    //    write it only after Bar5(t), readers finished pre-Bar2(t) — OK.
    //  h1s: gh1 reads pre-Bar3; B-epi writes post-Bar3; gi2 reads post-Bar4;
    //    next gh1(t+1) reads post-Bar2(t+1) — OK.
    //  scBi/scBh: W pre-Bar3 / R post-Bar3; next W post-Bar2(t+1) — OK.
    //  h2s: gh2 reads pre-Bar5; combine writes post-Bar5; next gh2 post-Bar4(t+1) — OK.
    //  scC: W pre-Bar5 / R post-Bar5; next W post-Bar4(t+1) — OK.
    //  Bit-exactness: every accumulator keeps R9's k-ascending order and partial
    //    boundaries; all combine orders replicated branch-for-branch.
  }
}

extern "C" void kernel_launch(void* const* d_in, const int* in_sizes, int n_in,
                              void* d_out, int out_size, void* d_ws, size_t ws_size,
                              hipStream_t stream) {
  const float* latent  = (const float*)d_in[0];
  const int*   tgt     = (const int*)d_in[1];
  const float* Wemb    = (const float*)d_in[2];
  const float* bemb    = (const float*)d_in[3];
  const float* Winit   = (const float*)d_in[4];
  const float* binit   = (const float*)d_in[5];
  const float* Wih0    = (const float*)d_in[6];
  const float* Whh0    = (const float*)d_in[7];
  const float* bih0    = (const float*)d_in[8];
  const float* bhh0    = (const float*)d_in[9];
  const float* Wih1    = (const float*)d_in[10];
  const float* Whh1    = (const float*)d_in[11];
  const float* bih1    = (const float*)d_in[12];
  const float* bhh1    = (const float*)d_in[13];
  const float* Wih2    = (const float*)d_in[14];
  const float* Whh2    = (const float*)d_in[15];
  const float* bih2    = (const float*)d_in[16];
  const float* bhh2    = (const float*)d_in[17];
  const float* Wproj   = (const float*)d_in[18];
  const float* bproj   = (const float*)d_in[19];

  float* ws = (float*)d_ws;
  float* out = (float*)d_out;

  int setup_threads = WS_FLOATS;
  int setup_blocks = (setup_threads + 255) / 256;
  setup_kernel<<<setup_blocks, 256, 0, stream>>>(Whh0, Wih1, Whh1, Wih2, Whh2, Wproj,
                                                Wemb, bemb, Wih0, bih0, ws);

  gru_persist<<<BATCH / RT, NT, 0, stream>>>(latent, tgt, Winit, binit,
                                             bhh0, bih1, bhh1, bih2, bhh2, bproj,
                                             ws, out);
}

// Round 12
// 6855.759 us; speedup vs baseline: 6.2051x; 6.2051x over previous
//
#include <hip/hip_runtime.h>
#include <hip/hip_bf16.h>

// Problem constants
#define BATCH 1024
#define SEQ   350
#define LAT   512
#define VOC   41
#define H0D   512
#define H1D   256
#define H2D   128
#define H3D   32
#define G1    768   // 3*H1D
#define G2    384   // 3*H2D
#define G3    96    // 3*H3D
#define SOS   1

// ws layout (floats) — PLANAR k-major (proven; R3/R10 showed any interleaving
// doubles FETCH and regresses).
#define O_HH0   0         // wt_hh0 [256k][768]
#define O_IH1   196608    // wt_ih1 [256k][384]
#define O_HH1   294912    // wt_hh1 [128k][384]
#define O_IH2   344064    // wt_ih2 [128k][96]
#define O_HH2   356352    // wt_hh2 [32k][96]
#define O_PROJ  359424    // wt_proj [32][41]
#define O_TAB   360736    // gi0 table [41][768]
#define WS_FLOATS 392224

#define RT 4    // batch rows per block
#define NT 512  // threads per block (8 waves)

__global__ void setup_kernel(const float* __restrict__ Whh0, const float* __restrict__ Wih1,
                             const float* __restrict__ Whh1, const float* __restrict__ Wih2,
                             const float* __restrict__ Whh2, const float* __restrict__ Wproj,
                             const float* __restrict__ Wemb, const float* __restrict__ bemb,
                             const float* __restrict__ Wih0, const float* __restrict__ bih0,
                             float* __restrict__ ws) {
  int idx = blockIdx.x * blockDim.x + threadIdx.x;
  if (idx < 196608) { int o = idx % G1, k = idx / G1; ws[O_HH0 + k*G1 + o] = Whh0[o*H1D + k]; return; }
  idx -= 196608;
  if (idx < 98304)  { int o = idx % G2, k = idx / G2; ws[O_IH1 + k*G2 + o] = Wih1[o*H1D + k]; return; }
  idx -= 98304;
  if (idx < 49152)  { int o = idx % G2, k = idx / G2; ws[O_HH1 + k*G2 + o] = Whh1[o*H2D + k]; return; }
  idx -= 49152;
  if (idx < 12288)  { int o = idx % G3, k = idx / G3; ws[O_IH2 + k*G3 + o] = Wih2[o*H2D + k]; return; }
  idx -= 12288;
  if (idx < 3072)   { int o = idx % G3, k = idx / G3; ws[O_HH2 + k*G3 + o] = Whh2[o*H3D + k]; return; }
  idx -= 3072;
  if (idx < 1312)   { int o = idx % VOC, k = idx / VOC; ws[O_PROJ + k*VOC + o] = Wproj[o*H3D + k]; return; }
  idx -= 1312;
  if (idx < 31488) {
    // gi0 table: exact (f64-accumulated) x@Wih0.T + bih0 per token value.
    int o = idx % G1, v = idx / G1;
    double acc = (double)bih0[o];
    const float* wrow = Wih0 + (size_t)o * H0D;
    for (int k = 0; k < H0D; ++k)
      acc += ((double)Wemb[k*VOC + v] + (double)bemb[k]) * (double)wrow[k];
    ws[O_TAB + v*G1 + o] = (float)acc;
  }
}

__device__ __forceinline__ float sigf(float x) { return 1.0f / (1.0f + expf(-x)); }

__global__ __launch_bounds__(NT) void gru_persist(
    const float* __restrict__ latent, const int* __restrict__ tgt,
    const float* __restrict__ Winit, const float* __restrict__ binit,
    const float* __restrict__ bhh0,
    const float* __restrict__ bih1, const float* __restrict__ bhh1,
    const float* __restrict__ bih2, const float* __restrict__ bhh2,
    const float* __restrict__ bproj,
    const float* __restrict__ ws, float* __restrict__ out)
{
  const int tid = threadIdx.x;
  const int r0 = blockIdx.x * RT;
  const int lane = tid & 63;
  const int wv = tid >> 6;   // wave id 0..7

  const float* wt_hh0 = ws + O_HH0;
  const float* wt_ih1 = ws + O_IH1;
  const float* wt_hh1 = ws + O_HH1;
  const float* wt_ih2 = ws + O_IH2;
  const float* wt_hh2 = ws + O_HH2;
  const float* wt_proj = ws + O_PROJ;
  const float* tab = ws + O_TAB;

  float* __restrict__ out_logits = out;
  float* __restrict__ out_pred = out + (size_t)BATCH * SEQ * VOC;

  __shared__ __align__(16) float h0s[2][RT][H1D];  // 8 KB (double-buffered)
  __shared__ __align__(16) float h1s[RT][H2D];     // 2 KB
  __shared__ __align__(16) float h2s[RT][H3D];     // 0.5 KB
  __shared__ float scBi[2][RT][3][H2D];   // 12 KB  (gi1 halves)
  __shared__ float scBh[2][RT][3][H2D];   // 12 KB  (gh1 halves)
  __shared__ float scC[10][3][RT][H3D];   // 15 KB  (stage C partials)
  __shared__ float projS[H3D * VOC];      // 5.1 KB
  __shared__ int   toksAll[RT][SEQ];      // 5.5 KB
  // total ~61 KB

  // ---- Stage A wave-local mapping (R9 verbatim)
  const int jA  = (wv << 5) + (lane & 31);
  const int kh  = lane >> 5;          // 0/1
  const int kA0 = kh << 7;            // 0 or 128
  const int rbA = kh << 1;            // epilogue rows {0,1} or {2,3}
  // Stage B/C mappings (R7/R9 verbatim)
  const int jb = tid & 127;
  const int g  = tid >> 7;
  const int jc = tid & 31;
  const int sc = tid >> 5;   // 0..15

  // ---- t-invariant f32 biases
  const float bA_r = bhh0[jA], bA_z = bhh0[256 + jA], bA_n = bhh0[512 + jA];
  const float bB_ir = bih1[jb], bB_iz = bih1[128 + jb], bB_in = bih1[256 + jb];
  const float bB_hr = bhh1[jb], bB_hz = bhh1[128 + jb], bB_hn = bhh1[256 + jb];
  const int jj2 = lane & 31;
  const float bC_ir = bih2[jj2], bC_iz = bih2[32 + jj2], bC_in = bih2[64 + jj2];
  const float bC_hr = bhh2[jj2], bC_hz = bhh2[32 + jj2], bC_hn = bhh2[64 + jj2];
  const int cpr = (lane < VOC) ? lane : 0;
  const float bP = bproj[cpr];

  // ---- one-time staging: tokens (SOS at t=0) and projection weights into LDS
  for (int i = tid; i < RT * SEQ; i += NT) {
    int r = i / SEQ, tt = i - r * SEQ;
    toksAll[r][tt] = (tt == 0) ? SOS : tgt[(size_t)(r0 + r) * SEQ + tt];
  }
  for (int i = tid; i < H3D * VOC; i += NT) projS[i] = wt_proj[i];

  // ---- init hidden states (f64, one-time; exact early-step logits)
  for (int idx = tid; idx < RT * 416; idx += NT) {
    int r = idx / 416, jj = idx - r * 416;
    const float* lrow = latent + (size_t)(r0 + r) * LAT;
    const float* wrow = Winit + (size_t)jj * LAT;
    double acc = (double)binit[jj];
    for (int k = 0; k < LAT; ++k) acc += (double)lrow[k] * (double)wrow[k];
    float a = (float)acc;
    if (jj < H1D) h0s[0][r][jj] = a;
    else if (jj < H1D + H2D) h1s[r][jj - H1D] = a;
    else h2s[r][jj - H1D - H2D] = a;
  }
  __syncthreads();

  int cur0 = 0;

  for (int t = 0; t < SEQ; ++t) {
    // ======== Stage A: GRU0, wave-local, K-loop unrolled x8 with hoisted weight
    //          loads (24 in flight). Per-accumulator FMA order = ascending k,
    //          identical to R9 -> bit-exact. ========
    {
      const float* trow0 = tab + (size_t)toksAll[rbA][t] * G1;
      const float* trow1 = tab + (size_t)toksAll[rbA + 1][t] * G1;
      const float t0x = trow0[jA], t0y = trow0[256 + jA], t0z = trow0[512 + jA];
      const float t1x = trow1[jA], t1y = trow1[256 + jA], t1z = trow1[512 + jA];

      float aR[RT], aZ[RT], aN[RT];
      #pragma unroll
      for (int r = 0; r < RT; ++r) { aR[r] = 0.0f; aZ[r] = 0.0f; aN[r] = 0.0f; }
      const float* __restrict__ wbase = wt_hh0 + jA;
      for (int kb = kA0; kb < kA0 + 128; kb += 8) {
        float wr8[8], wz8[8], wn8[8];
        #pragma unroll
        for (int u = 0; u < 8; ++u) {
          const float* wp = wbase + (size_t)(kb + u) * G1;
          wr8[u] = wp[0]; wz8[u] = wp[256]; wn8[u] = wp[512];
        }
        float4 hv0[RT], hv1[RT];
        #pragma unroll
        for (int r = 0; r < RT; ++r) {
          hv0[r] = *(const float4*)&h0s[cur0][r][kb];
          hv1[r] = *(const float4*)&h0s[cur0][r][kb + 4];
        }
        #pragma unroll
        for (int u = 0; u < 8; ++u) {
          #pragma unroll
          for (int r = 0; r < RT; ++r) {
            const float hval = (u < 4) ? ((const float*)&hv0[r])[u]
                                       : ((const float*)&hv1[r])[u - 4];
            aR[r] = fmaf(hval, wr8[u], aR[r]);
            aZ[r] = fmaf(hval, wz8[u], aZ[r]);
            aN[r] = fmaf(hval, wn8[u], aN[r]);
          }
        }
      }
      // other K-half via shfl; all 64 lanes participate.
      float oR[RT], oZ[RT], oN[RT];
      #pragma unroll
      for (int r = 0; r < RT; ++r) {
        oR[r] = __shfl_xor(aR[r], 32);
        oZ[r] = __shfl_xor(aZ[r], 32);
        oN[r] = __shfl_xor(aN[r], 32);
      }
      // Epilogue, association identical to R7/R9: ((tx + own) + other) + b.
#define EPIA(r, tx, ty, tz)                                                \
      {                                                                    \
        const float gR  = tx + aR[r] + oR[r] + bA_r;                       \
        const float gZ  = ty + aZ[r] + oZ[r] + bA_z;                       \
        const float ghN =      aN[r] + oN[r] + bA_n;                       \
        const float rg = sigf(gR);                                         \
        const float zg = sigf(gZ);                                         \
        const float ng = tanhf(fmaf(rg, ghN, tz));                         \
        h0s[cur0 ^ 1][r][jA] = (1.0f - zg) * ng + zg * h0s[cur0][r][jA];   \
      }
      if (lane < 32) {
        EPIA(0, t0x, t0y, t0z)
        EPIA(1, t1x, t1y, t1z)
      } else {
        EPIA(2, t0x, t0y, t0z)
        EPIA(3, t1x, t1y, t1z)
      }
#undef EPIA
    }
    __syncthreads();  // B2: h0 new (h0s[cur0^1]) visible to all

    // ======== Stage B: GRU1 (R9 structure; K-loops unrolled x8, hoisted loads). ========
    {
      float bR[RT], bZ[RT], bN[RT];
      #pragma unroll
      for (int r = 0; r < RT; ++r) { bR[r] = 0.0f; bZ[r] = 0.0f; bN[r] = 0.0f; }
      if (g < 2) {
        const float* __restrict__ wbase = wt_ih1 + jb;
        const int k0 = g * 128;
        for (int kb = k0; kb < k0 + 128; kb += 8) {
          float wr8[8], wz8[8], wn8[8];
          #pragma unroll
          for (int u = 0; u < 8; ++u) {
            const float* wp = wbase + (size_t)(kb + u) * G2;
            wr8[u] = wp[0]; wz8[u] = wp[128]; wn8[u] = wp[256];
          }
          float4 hv0[RT], hv1[RT];
          #pragma unroll
          for (int r = 0; r < RT; ++r) {
            hv0[r] = *(const float4*)&h0s[cur0 ^ 1][r][kb];
            hv1[r] = *(const float4*)&h0s[cur0 ^ 1][r][kb + 4];
          }
          #pragma unroll
          for (int u = 0; u < 8; ++u) {
            #pragma unroll
            for (int r = 0; r < RT; ++r) {
              const float hval = (u < 4) ? ((const float*)&hv0[r])[u]
                                         : ((const float*)&hv1[r])[u - 4];
              bR[r] = fmaf(hval, wr8[u], bR[r]);
              bZ[r] = fmaf(hval, wz8[u], bZ[r]);
              bN[r] = fmaf(hval, wn8[u], bN[r]);
            }
          }
        }
        #pragma unroll
        for (int r = 0; r < RT; ++r) {
          scBi[g][r][0][jb] = bR[r];
          scBi[g][r][1][jb] = bZ[r];
          scBi[g][r][2][jb] = bN[r];
        }
      } else {
        const float* __restrict__ wbase = wt_hh1 + jb;
        const int k0 = (g - 2) * 64;
        for (int kb = k0; kb < k0 + 64; kb += 8) {
          float wr8[8], wz8[8], wn8[8];
          #pragma unroll
          for (int u = 0; u < 8; ++u) {
            const float* wp = wbase + (size_t)(kb + u) * G2;
            wr8[u] = wp[0]; wz8[u] = wp[128]; wn8[u] = wp[256];
          }
          float4 hv0[RT], hv1[RT];
          #pragma unroll
          for (int r = 0; r < RT; ++r) {
            hv0[r] = *(const float4*)&h1s[r][kb];
            hv1[r] = *(const float4*)&h1s[r][kb + 4];
          }
          #pragma unroll
          for (int u = 0; u < 8; ++u) {
            #pragma unroll
            for (int r = 0; r < RT; ++r) {
              const float hval = (u < 4) ? ((const float*)&hv0[r])[u]
                                         : ((const float*)&hv1[r])[u - 4];
              bR[r] = fmaf(hval, wr8[u], bR[r]);
              bZ[r] = fmaf(hval, wz8[u], bZ[r]);
              bN[r] = fmaf(hval, wn8[u], bN[r]);
            }
          }
        }
        #pragma unroll
        for (int r = 0; r < RT; ++r) {
          scBh[g - 2][r][0][jb] = bR[r];
          scBh[g - 2][r][1][jb] = bZ[r];
          scBh[g - 2][r][2][jb] = bN[r];
        }
      }
      __syncthreads();  // B3: partials visible; all h1s reads done
      if (g >= 2) {
        const int rb = (g - 2) * 2;
        const int oh = 3 - g;
        #pragma unroll
        for (int e = 0; e < 2; ++e) {
          const int r = rb + e;
          const float giR = scBi[0][r][0][jb] + scBi[1][r][0][jb] + bB_ir;
          const float giZ = scBi[0][r][1][jb] + scBi[1][r][1][jb] + bB_iz;
          const float giN = scBi[0][r][2][jb] + scBi[1][r][2][jb] + bB_in;
          const float ghR = bR[r] + scBh[oh][r][0][jb] + bB_hr;
          const float ghZ = bZ[r] + scBh[oh][r][1][jb] + bB_hz;
          const float ghN = bN[r] + scBh[oh][r][2][jb] + bB_hn;
          const float rg = sigf(giR + ghR);
          const float zg = sigf(giZ + ghZ);
          const float ng = tanhf(fmaf(rg, ghN, giN));
          h1s[r][jb] = (1.0f - zg) * ng + zg * h1s[r][jb];
        }
      }
    }
    __syncthreads();  // B4: h1 new visible

    // ======== Stage C: GRU2 (R9 verbatim). ========
    {
      float cR[RT], cZ[RT], cN[RT];
      #pragma unroll
      for (int r = 0; r < RT; ++r) { cR[r] = 0.0f; cZ[r] = 0.0f; cN[r] = 0.0f; }
      if (sc < 8) {
        for (int kk = 0; kk < 16; ++kk) {
          int k = sc * 16 + kk;
          const float* wp = wt_ih2 + (size_t)k * G3;
          const float wr = wp[jc], wz = wp[32 + jc], wn = wp[64 + jc];
          #pragma unroll
          for (int r = 0; r < RT; ++r) {
            const float hval = h1s[r][k];
            cR[r] = fmaf(hval, wr, cR[r]);
            cZ[r] = fmaf(hval, wz, cZ[r]);
            cN[r] = fmaf(hval, wn, cN[r]);
          }
        }
      } else if (sc < 10) {
        for (int kk = 0; kk < 16; ++kk) {
          int k = (sc - 8) * 16 + kk;
          const float* wp = wt_hh2 + (size_t)k * G3;
          const float wr = wp[jc], wz = wp[32 + jc], wn = wp[64 + jc];
          #pragma unroll
          for (int r = 0; r < RT; ++r) {
            const float hval = h2s[r][k];
            cR[r] = fmaf(hval, wr, cR[r]);
            cZ[r] = fmaf(hval, wz, cZ[r]);
            cN[r] = fmaf(hval, wn, cN[r]);
          }
        }
      }
      if (sc < 10) {
        #pragma unroll
        for (int r = 0; r < RT; ++r) {
          scC[sc][0][r][jc] = cR[r];
          scC[sc][1][r][jc] = cZ[r];
          scC[sc][2][r][jc] = cN[r];
        }
      }
    }
    __syncthreads();  // B5: scC partials visible; all h2s(old) reads done

    // ======== Stage C combine + projection + argmax, waves 0-3 (one row each);
    //          waves 4-7 fall through into stage A of t+1 (sync via B2(t+1)). ========
    if (wv < 4) {
      const int r = wv;
      float h2f = 0.0f;
      if (lane < 32) {
        const int jj = lane;
        float giR = bC_ir, giZ = bC_iz, giN = bC_in;
        #pragma unroll
        for (int s = 0; s < 8; ++s) {
          giR += scC[s][0][r][jj];
          giZ += scC[s][1][r][jj];
          giN += scC[s][2][r][jj];
        }
        const float ghR = scC[8][0][r][jj] + scC[9][0][r][jj] + bC_hr;
        const float ghZ = scC[8][1][r][jj] + scC[9][1][r][jj] + bC_hz;
        const float ghN = scC[8][2][r][jj] + scC[9][2][r][jj] + bC_hn;
        const float rg = sigf(giR + ghR);
        const float zg = sigf(giZ + ghZ);
        const float ng = tanhf(fmaf(rg, ghN, giN));
        h2f = (1.0f - zg) * ng + zg * h2s[r][jj];
        h2s[r][jj] = h2f;
      }
      float acc = bP;
      #pragma unroll
      for (int k = 0; k < H3D; ++k) {
        const float hk = __shfl(h2f, k);
        acc = fmaf(hk, projS[k * VOC + cpr], acc);
      }
      if (lane < VOC)
        out_logits[((size_t)(r0 + r) * SEQ + t) * VOC + lane] = acc;
      float val = (lane < VOC) ? acc : -3.402823466e38f;
      int idx = lane;
      #pragma unroll
      for (int off = 32; off > 0; off >>= 1) {
        const float ov = __shfl_xor(val, off);
        const int   oi = __shfl_xor(idx, off);
        if (ov > val || (ov == val && oi < idx)) { val = ov; idx = oi; }
      }
      if (lane == 0)
        out_pred[(size_t)(r0 + r) * SEQ + t] = (float)idx;
    }
    cur0 ^= 1;
    // Hazard audit: identical to R9 (only in-loop scheduling changed; all
    // buffer writers/readers and barriers unchanged).
  }
}

extern "C" void kernel_launch(void* const* d_in, const int* in_sizes, int n_in,
                              void* d_out, int out_size, void* d_ws, size_t ws_size,
                              hipStream_t stream) {
  const float* latent  = (const float*)d_in[0];
  const int*   tgt     = (const int*)d_in[1];
  const float* Wemb    = (const float*)d_in[2];
  const float* bemb    = (const float*)d_in[3];
  const float* Winit   = (const float*)d_in[4];
  const float* binit   = (const float*)d_in[5];
  const float* Wih0    = (const float*)d_in[6];
  const float* Whh0    = (const float*)d_in[7];
  const float* bih0    = (const float*)d_in[8];
  const float* bhh0    = (const float*)d_in[9];
  const float* Wih1    = (const float*)d_in[10];
  const float* Whh1    = (const float*)d_in[11];
  const float* bih1    = (const float*)d_in[12];
  const float* bhh1    = (const float*)d_in[13];
  const float* Wih2    = (const float*)d_in[14];
  const float* Whh2    = (const float*)d_in[15];
  const float* bih2    = (const float*)d_in[16];
  const float* bhh2    = (const float*)d_in[17];
  const float* Wproj   = (const float*)d_in[18];
  const float* bproj   = (const float*)d_in[19];

  float* ws = (float*)d_ws;
  float* out = (float*)d_out;

  int setup_threads = WS_FLOATS;
  int setup_blocks = (setup_threads + 255) / 256;
  setup_kernel<<<setup_blocks, 256, 0, stream>>>(Whh0, Wih1, Whh1, Wih2, Whh2, Wproj,
                                                Wemb, bemb, Wih0, bih0, ws);

  gru_persist<<<BATCH / RT, NT, 0, stream>>>(latent, tgt, Winit, binit,
                                             bhh0, bih1, bhh1, bih2, bhh2, bproj,
                                             ws, out);
}